// Round 9
// baseline (63.921 us; speedup 1.0000x reference)
//
#include <hip/hip_runtime.h>
#include <cstddef>
#include <cstdint>

#define D_MODEL 512
#define DK 64
#define LQ 1024
#define LK 1024
#define NB 2
#define LN_EPS 1e-6f
#define L2E2 2.8853900817779268f  // 2*log2(e)

// pack two floats to bf16x2 (RNE), low word = a
__device__ __forceinline__ uint32_t pack_bf2(float a, float b) {
  uint32_t ua = __float_as_uint(a), ub = __float_as_uint(b);
  ua = (ua + 0x7fffu + ((ua >> 16) & 1u)) >> 16;
  ub = (ub + 0x7fffu + ((ub >> 16) & 1u)) >> 16;
  return (ub << 16) | ua;
}

// ---------------- projections ----------------
// type 0: qp=q@Wq -> ab_g[row][d] = {v_d*e^{-2qp}, e^{-2qp}}
// type 1: ek=e^{2*(k@Wk)} -> ekT[batch][dp][j] u32 = bf16{ek[dp], ek[dp+32]}
// type 2: vp = v@Wv (f32 row-major)
// 256 thr (4 waves), 16 rows/block (4 rows/wave), grid 3*128=384.
// 4 rows/wave halves the per-row W L2 stream vs 2 rows/wave (r8 bottleneck).
#define PR_ROWS 16
__global__ __launch_bounds__(256, 4) void proj_kernel(
    const float* __restrict__ q, const float* __restrict__ k,
    const float* __restrict__ v, const float* __restrict__ Wq,
    const float* __restrict__ Wk, const float* __restrict__ Wv,
    const float* __restrict__ v_param, float2* __restrict__ ab_g,
    uint32_t* __restrict__ ekT, float* __restrict__ vp) {
  __shared__ float rows[PR_ROWS][D_MODEL];  // 32 KB
  const int tid = threadIdx.x;
  const int type = blockIdx.x >> 7;  // 128 row-groups per type
  const int r0 = (blockIdx.x & 127) * PR_ROWS;
  const float* __restrict__ in = (type == 0) ? q : (type == 1) ? k : v;
  const float* __restrict__ W = (type == 0) ? Wq : (type == 1) ? Wk : Wv;
  {
    const float4* __restrict__ in4 = (const float4*)(in + (size_t)r0 * D_MODEL);
    float4* r4 = (float4*)&rows[0][0];
#pragma unroll
    for (int t = 0; t < 8; ++t) r4[tid + 256 * t] = in4[tid + 256 * t];
  }
  __syncthreads();
  const int lane = tid & 63;
  const int wv = tid >> 6;        // 0..3
  const int rglob = r0 + wv * 4;  // wave's first global row (mult of 4)
  const float* __restrict__ Wl = W + lane;
  float c0[4] = {0.f, 0.f, 0.f, 0.f}, c1[4] = {0.f, 0.f, 0.f, 0.f};
#pragma unroll 2
  for (int e = 0; e < D_MODEL; e += 4) {
    float w0 = Wl[(size_t)(e + 0) * DK];
    float w1 = Wl[(size_t)(e + 1) * DK];
    float w2 = Wl[(size_t)(e + 2) * DK];
    float w3 = Wl[(size_t)(e + 3) * DK];
#pragma unroll
    for (int r = 0; r < 4; ++r) {
      float4 x = *(const float4*)&rows[wv * 4 + r][e];
      c0[r] = fmaf(x.x, w0, c0[r]);
      c1[r] = fmaf(x.y, w1, c1[r]);
      c0[r] = fmaf(x.z, w2, c0[r]);
      c1[r] = fmaf(x.w, w3, c1[r]);
    }
  }
  float acc[4];
#pragma unroll
  for (int r = 0; r < 4; ++r) acc[r] = c0[r] + c1[r];
  if (type == 0) {
    float vpar = v_param[lane];
#pragma unroll
    for (int r = 0; r < 4; ++r) {
      float iv = __builtin_amdgcn_exp2f(-L2E2 * acc[r]);
      ab_g[(size_t)(rglob + r) * DK + lane] = make_float2(vpar * iv, iv);
    }
  } else if (type == 1) {
    float e4[4], h4[4];
#pragma unroll
    for (int r = 0; r < 4; ++r) {
      e4[r] = __builtin_amdgcn_exp2f(L2E2 * acc[r]);
      h4[r] = __shfl_down(e4[r], 32);  // lane d gets Ek[d+32]
    }
    if (lane < 32) {
      int b = rglob >> 10, j0 = rglob & 1023;  // rglob%4==0 -> 16B aligned
      uint4 pk;
      pk.x = pack_bf2(e4[0], h4[0]);
      pk.y = pack_bf2(e4[1], h4[1]);
      pk.z = pack_bf2(e4[2], h4[2]);
      pk.w = pack_bf2(e4[3], h4[3]);
      *(uint4*)&ekT[(size_t)b * 32 * LK + (size_t)lane * LK + j0] = pk;
    }
  } else {
#pragma unroll
    for (int r = 0; r < 4; ++r) vp[(size_t)(rglob + r) * DK + lane] = acc[r];
  }
}

// ---------------- scores + softmax -> P (attn_out) ----------------
// 256 thr (4 waves), RB=4 rows, grid 512, ~6 blocks/CU (LDS 2KB).
// Thread owns FOUR j columns (tid + 256*jj): one ab4s broadcast serves 4 j.
// Softmax entirely in registers; only 2 tiny cross-wave LDS reduces.
#define RB 4
__global__ __launch_bounds__(256, 6) void score_kernel(
    const float2* __restrict__ ab_g, const uint32_t* __restrict__ ekT,
    float* __restrict__ attn_out) {
  __shared__ float4 ab4s[RB][32];  // 2 KB {A,B,A',B'}
  __shared__ float mred[RB][4], sred[RB][4];
  const int tid = threadIdx.x;
  const int row0 = blockIdx.x * RB;  // RB | LQ -> single batch per block
  const int batch = row0 >> 10;
  const uint32_t* __restrict__ ekT_b = ekT + (size_t)batch * 32 * LK;
  {
    int r = tid >> 6, d = tid & 63;
    float2 abv = ab_g[(size_t)(row0 + r) * DK + d];
    ((float2*)&ab4s[r][d & 31])[d >> 5] = abv;
  }
  __syncthreads();

  float acc[RB][4];
#pragma unroll
  for (int r = 0; r < RB; ++r)
#pragma unroll
    for (int jj = 0; jj < 4; ++jj) acc[r][jj] = 0.f;

#pragma unroll 2
  for (int dp = 0; dp < 32; ++dp) {
    float klo[4], khi[4];
#pragma unroll
    for (int jj = 0; jj < 4; ++jj) {
      uint32_t kw = ekT_b[(size_t)dp * LK + tid + jj * 256];
      klo[jj] = __uint_as_float(kw << 16);
      khi[jj] = __uint_as_float(kw & 0xffff0000u);
    }
#pragma unroll
    for (int r = 0; r < RB; ++r) {
      float4 ab = ab4s[r][dp];  // one broadcast serves 4 j
#pragma unroll
      for (int jj = 0; jj < 4; ++jj) {
        float x1 = klo[jj] + ab.y, x2 = khi[jj] + ab.w;
        float num = fmaf(ab.z, x1, ab.x * x2);
        acc[r][jj] = fmaf(num, __builtin_amdgcn_rcpf(x1 * x2), acc[r][jj]);
      }
    }
  }

  const int wave = __builtin_amdgcn_readfirstlane(tid >> 6);
  const int lane = tid & 63;

  // softmax over score = C - 2*acc -> shift by min(acc)
  {
#pragma unroll
    for (int r = 0; r < RB; ++r) {
      float pm = fminf(fminf(acc[r][0], acc[r][1]), fminf(acc[r][2], acc[r][3]));
#pragma unroll
      for (int off = 32; off > 0; off >>= 1) pm = fminf(pm, __shfl_xor(pm, off));
      if (lane == 0) mred[r][wave] = pm;
    }
    __syncthreads();
    float inv[RB];
#pragma unroll
    for (int r = 0; r < RB; ++r) {
      float m = fminf(fminf(mred[r][0], mred[r][1]),
                      fminf(mred[r][2], mred[r][3]));
      float s = 0.f;
#pragma unroll
      for (int jj = 0; jj < 4; ++jj) {
        float e = __builtin_amdgcn_exp2f((m - acc[r][jj]) * L2E2);
        acc[r][jj] = e;
        s += e;
      }
#pragma unroll
      for (int off = 32; off > 0; off >>= 1) s += __shfl_xor(s, off);
      if (lane == 0) sred[r][wave] = s;
    }
    __syncthreads();
#pragma unroll
    for (int r = 0; r < RB; ++r)
      inv[r] = __builtin_amdgcn_rcpf(sred[r][0] + sred[r][1] + sred[r][2] +
                                     sred[r][3]);
#pragma unroll
    for (int r = 0; r < RB; ++r) {
      float* __restrict__ arow = attn_out + (size_t)(row0 + r) * LK;
#pragma unroll
      for (int jj = 0; jj < 4; ++jj)
        arow[tid + jj * 256] = acc[r][jj] * inv[r];
    }
  }
}

// ---------------- PV + FC + LN ----------------
// 256 thr (4 waves), RB=4 rows, grid 512. P staged from attn_out (L2-warm).
__global__ __launch_bounds__(256, 4) void pvfc_kernel(
    const float* __restrict__ attn, const float* __restrict__ vp,
    const float* __restrict__ resid, const float* __restrict__ Wfc,
    const float* __restrict__ gamma, const float* __restrict__ beta,
    float* __restrict__ out) {
  __shared__ float sc[RB][LK];                  // 16 KB P rows
  __shared__ float4 pvred[4][RB][16];           // 4 KB PV partials
  __shared__ __align__(16) float ovlT[DK][RB];  // 1 KB, e-major
  __shared__ float red[2][RB][4];               // LN reductions
  const int tid = threadIdx.x;
  const int row0 = blockIdx.x * RB;
  const int batch = row0 >> 10;
  const float* __restrict__ vp_b = vp + (size_t)batch * LK * DK;
  {
    const float4* __restrict__ a4 =
        (const float4*)(attn + (size_t)row0 * LK);
    float4* s4 = (float4*)&sc[0][0];
#pragma unroll
    for (int t = 0; t < 4; ++t) s4[tid + 256 * t] = a4[tid + 256 * t];
  }
  __syncthreads();

  const int wave = __builtin_amdgcn_readfirstlane(tid >> 6);
  const int lane = tid & 63;

  // PV: wave owns 256-j slice; vp read once per block per j (serves 4 rows)
  {
    const int jj = lane >> 4, l16 = lane & 15;
    const float4* __restrict__ vp4 = (const float4*)vp_b;
    float4 a[RB];
#pragma unroll
    for (int r = 0; r < RB; ++r) a[r] = make_float4(0.f, 0.f, 0.f, 0.f);
#pragma unroll 4
    for (int it = 0; it < 64; ++it) {
      int j = (wave << 8) + (it << 2) + jj;
      float4 vv = vp4[(size_t)j * (DK / 4) + l16];
#pragma unroll
      for (int r = 0; r < RB; ++r) {
        float pw = sc[r][j];
        a[r].x = fmaf(pw, vv.x, a[r].x);
        a[r].y = fmaf(pw, vv.y, a[r].y);
        a[r].z = fmaf(pw, vv.z, a[r].z);
        a[r].w = fmaf(pw, vv.w, a[r].w);
      }
    }
#pragma unroll
    for (int r = 0; r < RB; ++r) {
      a[r].x += __shfl_xor(a[r].x, 16); a[r].y += __shfl_xor(a[r].y, 16);
      a[r].z += __shfl_xor(a[r].z, 16); a[r].w += __shfl_xor(a[r].w, 16);
      a[r].x += __shfl_xor(a[r].x, 32); a[r].y += __shfl_xor(a[r].y, 32);
      a[r].z += __shfl_xor(a[r].z, 32); a[r].w += __shfl_xor(a[r].w, 32);
    }
    if (jj == 0) {
#pragma unroll
      for (int r = 0; r < RB; ++r) pvred[wave][r][l16] = a[r];
    }
  }
  __syncthreads();
  if (tid < 64) {  // final PV reduce -> transposed ovlT[e][r]
    int r = tid >> 4, l16 = tid & 15;
    float4 s = make_float4(0.f, 0.f, 0.f, 0.f);
#pragma unroll
    for (int w = 0; w < 4; ++w) {
      float4 t = pvred[w][r][l16];
      s.x += t.x; s.y += t.y; s.z += t.z; s.w += t.w;
    }
    ovlT[l16 * 4 + 0][r] = s.x;
    ovlT[l16 * 4 + 1][r] = s.y;
    ovlT[l16 * 4 + 2][r] = s.z;
    ovlT[l16 * 4 + 3][r] = s.w;
  }
  __syncthreads();

  // FC + residual + LN: thread owns columns c, c+256 of 4 rows
  {
    const int c0 = tid, c1 = tid + 256;
    float y[RB][2];
#pragma unroll
    for (int r = 0; r < RB; ++r) {
      y[r][0] = resid[(size_t)(row0 + r) * D_MODEL + c0];
      y[r][1] = resid[(size_t)(row0 + r) * D_MODEL + c1];
    }
#pragma unroll 4
    for (int e = 0; e < DK; ++e) {
      float w0 = Wfc[(size_t)e * D_MODEL + c0];
      float w1 = Wfc[(size_t)e * D_MODEL + c1];
      float4 ov = *(const float4*)&ovlT[e][0];
      y[0][0] = fmaf(ov.x, w0, y[0][0]); y[0][1] = fmaf(ov.x, w1, y[0][1]);
      y[1][0] = fmaf(ov.y, w0, y[1][0]); y[1][1] = fmaf(ov.y, w1, y[1][1]);
      y[2][0] = fmaf(ov.z, w0, y[2][0]); y[2][1] = fmaf(ov.z, w1, y[2][1]);
      y[3][0] = fmaf(ov.w, w0, y[3][0]); y[3][1] = fmaf(ov.w, w1, y[3][1]);
    }
#pragma unroll
    for (int r = 0; r < RB; ++r) {
      float s = y[r][0] + y[r][1];
#pragma unroll
      for (int off = 32; off > 0; off >>= 1) s += __shfl_xor(s, off);
      if (lane == 0) red[0][r][wave] = s;
    }
    __syncthreads();
    float mu[RB];
#pragma unroll
    for (int r = 0; r < RB; ++r)
      mu[r] = (red[0][r][0] + red[0][r][1] + red[0][r][2] + red[0][r][3]) *
              (1.0f / D_MODEL);
#pragma unroll
    for (int r = 0; r < RB; ++r) {
      float d0 = y[r][0] - mu[r], d1 = y[r][1] - mu[r];
      float s = d0 * d0 + d1 * d1;
#pragma unroll
      for (int off = 32; off > 0; off >>= 1) s += __shfl_xor(s, off);
      if (lane == 0) red[1][r][wave] = s;
    }
    __syncthreads();
    float g0 = gamma[c0], g1 = gamma[c1], b0 = beta[c0], b1 = beta[c1];
#pragma unroll
    for (int r = 0; r < RB; ++r) {
      float var = (red[1][r][0] + red[1][r][1] + red[1][r][2] + red[1][r][3]) *
                  (1.0f / D_MODEL);
      float rstd = rsqrtf(var + LN_EPS);
      out[(size_t)(row0 + r) * D_MODEL + c0] = (y[r][0] - mu[r]) * rstd * g0 + b0;
      out[(size_t)(row0 + r) * D_MODEL + c1] = (y[r][1] - mu[r]) * rstd * g1 + b1;
    }
  }
}

extern "C" void kernel_launch(void* const* d_in, const int* in_sizes, int n_in,
                              void* d_out, int out_size, void* d_ws,
                              size_t ws_size, hipStream_t stream) {
  const float* q = (const float*)d_in[0];
  const float* k = (const float*)d_in[1];
  const float* v = (const float*)d_in[2];
  const float* Wq = (const float*)d_in[3];
  const float* Wk = (const float*)d_in[4];
  const float* Wv = (const float*)d_in[5];
  const float* v_param = (const float*)d_in[6];
  const float* Wfc = (const float*)d_in[7];
  const float* gamma = (const float*)d_in[8];
  const float* beta = (const float*)d_in[9];

  float* out = (float*)d_out;                     // [B*LQ*D_MODEL]
  float* attn = out + (size_t)NB * LQ * D_MODEL;  // [B*LQ*LK]

  float* base = (float*)d_ws;
  float2* ab_g = (float2*)base;                                  // [2048*64]
  uint32_t* ekT = (uint32_t*)(base + (size_t)2 * NB * LQ * DK);  // [2*32*1024]
  float* vp = base + (size_t)2 * NB * LQ * DK + NB * 32 * LK;    // [2048*64]

  hipLaunchKernelGGL(proj_kernel, dim3(3 * 128), dim3(256), 0, stream, q, k, v,
                     Wq, Wk, Wv, v_param, ab_g, ekT, vp);
  hipLaunchKernelGGL(score_kernel, dim3(NB * LQ / RB), dim3(256), 0, stream,
                     ab_g, ekT, attn);
  hipLaunchKernelGGL(pvfc_kernel, dim3(NB * LQ / RB), dim3(256), 0, stream,
                     attn, vp, q, Wfc, gamma, beta, out);
}